// Round 2
// baseline (833.176 us; speedup 1.0000x reference)
//
#include <hip/hip_runtime.h>
#include <stdint.h>

using bf16x8 = __attribute__((ext_vector_type(8))) __bf16;
using f32x4  = __attribute__((ext_vector_type(4))) float;

__device__ __forceinline__ unsigned short f2bf(float f) {
  unsigned u = __float_as_uint(f);
  u = u + 0x7FFFu + ((u >> 16) & 1u);
  return (unsigned short)(u >> 16);
}
__device__ __forceinline__ float bf2f(unsigned short h) {
  return __uint_as_float(((unsigned)h) << 16);
}
__device__ __forceinline__ void gload16(const void* g, void* l) {
  __builtin_amdgcn_global_load_lds((const __attribute__((address_space(1))) void*)g,
                                   (__attribute__((address_space(3))) void*)l, 16, 0, 0);
}

// ---------- cast f32 weights -> bf16 (1M elems, 4/thread) ----------
__global__ __launch_bounds__(256) void castw_kernel(const float* __restrict__ w,
                                                    unsigned short* __restrict__ o) {
  int i4 = blockIdx.x * 256 + threadIdx.x;
  float4 f = *(const float4*)(w + (size_t)i4 * 4);
  ushort4 u;
  u.x = f2bf(f.x); u.y = f2bf(f.y); u.z = f2bf(f.z); u.w = f2bf(f.w);
  *(ushort4*)(o + (size_t)i4 * 4) = u;
}

// ---------- token-shift mix (single variant): amix[row][c] = x*m + xs*(1-m)  (bf16) ----------
__global__ __launch_bounds__(256) void mix1_kernel(const float* __restrict__ x,
                                                   const float* __restrict__ m,
                                                   unsigned short* __restrict__ amix) {
  int idx = blockIdx.x * 256 + threadIdx.x;   // [0, 4M)
  int row = idx >> 8;
  int c0  = (idx & 255) << 2;
  size_t xoff = (size_t)row * 1024 + c0;
  float4 xv = *(const float4*)(x + xoff);
  float4 xs = make_float4(0.f, 0.f, 0.f, 0.f);
  if ((row & 2047) != 0) xs = *(const float4*)(x + xoff - 1024);
  float4 mm = *(const float4*)(m + c0);
  ushort4 u;
  u.x = f2bf(xv.x * mm.x + xs.x * (1.f - mm.x));
  u.y = f2bf(xv.y * mm.y + xs.y * (1.f - mm.y));
  u.z = f2bf(xv.z * mm.z + xs.z * (1.f - mm.z));
  u.w = f2bf(xv.w * mm.w + xs.w * (1.f - mm.w));
  *(ushort4*)(amix + xoff) = u;
}

// ---------- bf16 NT GEMM: C[M=16384,N=1024] = A[M,K=1024] @ W[N,K]^T ----------
// 128x128 tile, BK=32, 4 waves, m97 structure (global_load_lds width 16).
__global__ __launch_bounds__(256) void gemm_kernel(
    const unsigned short* __restrict__ A,
    const unsigned short* __restrict__ W,
    unsigned short* __restrict__ Cbf,
    float* __restrict__ Cf,
    int do_silu, int f32out) {
  const int brow = blockIdx.y * 128;
  const int bcol = blockIdx.x * 128;
  const int t = threadIdx.x;
  const int lane = t & 63, wv = t >> 6;
  const int wr = wv >> 1, wc = wv & 1;
  const int lm = lane & 15, lk = lane >> 4;

  __shared__ __align__(16) unsigned short Al[128 * 32];
  __shared__ __align__(16) unsigned short Bl[128 * 32];

  f32x4 acc[4][4];
  const f32x4 z4 = {0.f, 0.f, 0.f, 0.f};
  #pragma unroll
  for (int mi = 0; mi < 4; ++mi)
    #pragma unroll
    for (int ni = 0; ni < 4; ++ni) acc[mi][ni] = z4;

  for (int kt = 0; kt < 32; ++kt) {
    __syncthreads();   // all waves done reading previous tile
    #pragma unroll
    for (int is = 0; is < 2; ++is) {
      int chunk = is * 256 + t;          // 16B chunk id within 8KB half
      int r  = chunk >> 2;               // row (4 chunks per 64B row)
      int c8 = (chunk & 3) << 3;         // bf16 col start
      int lb = (is * 256 + wv * 64) * 8; // wave-uniform LDS base (ushort units)
      gload16(A + (size_t)(brow + r) * 1024 + kt * 32 + c8, &Al[lb]);
      gload16(W + (size_t)(bcol + r) * 1024 + kt * 32 + c8, &Bl[lb]);
    }
    __syncthreads();   // barrier drains vmcnt(0) -> tile resident
    bf16x8 af[4], bfv[4];
    #pragma unroll
    for (int mi = 0; mi < 4; ++mi)
      af[mi] = *(const bf16x8*)&Al[(wr * 64 + mi * 16 + lm) * 32 + lk * 8];
    #pragma unroll
    for (int ni = 0; ni < 4; ++ni)
      bfv[ni] = *(const bf16x8*)&Bl[(wc * 64 + ni * 16 + lm) * 32 + lk * 8];
    #pragma unroll
    for (int mi = 0; mi < 4; ++mi)
      #pragma unroll
      for (int ni = 0; ni < 4; ++ni)
        acc[mi][ni] = __builtin_amdgcn_mfma_f32_16x16x32_bf16(af[mi], bfv[ni], acc[mi][ni], 0, 0, 0);
  }

  const int r0 = brow + wr * 64;
  const int c0 = bcol + wc * 64;
  #pragma unroll
  for (int mi = 0; mi < 4; ++mi) {
    #pragma unroll
    for (int ni = 0; ni < 4; ++ni) {
      #pragma unroll
      for (int rg = 0; rg < 4; ++rg) {
        int row = r0 + mi * 16 + lk * 4 + rg;   // C/D: col=lane&15, row=(lane>>4)*4+reg (m89)
        int col = c0 + ni * 16 + lm;
        float v = acc[mi][ni][rg];
        if (f32out) {
          Cf[(size_t)row * 1024 + col] = v;
        } else {
          if (do_silu) v = v / (1.f + expf(-v));   // silu for the gate
          Cbf[(size_t)row * 1024 + col] = f2bf(v);
        }
      }
    }
  }
}

// ---------- scan pass 1: per-chunk local states (zero init) ----------
// grid (NC=16, H=16, B=8), block 256. wave wv owns k-slice [wv*16,wv*16+16), lane = v-col.
__global__ __launch_bounds__(256) void scan_pass1(
    const unsigned short* __restrict__ kg,
    const unsigned short* __restrict__ vg,
    const float* __restrict__ td,
    float* __restrict__ states) {
  const int c = blockIdx.x, h = blockIdx.y, b = blockIdx.z;
  const int t = threadIdx.x, lane = t & 63, wv = t >> 6;
  float w_i[16], s_i[16];
  #pragma unroll
  for (int i = 0; i < 16; ++i) {
    w_i[i] = expf(-expf(td[h * 64 + wv * 16 + i]));
    s_i[i] = 0.f;
  }
  __shared__ __align__(16) float kb[16][64];
  __shared__ __align__(16) float vb[16][64];
  const int t0 = c * 128;
  for (int q0 = 0; q0 < 128; q0 += 16) {
    __syncthreads();
    {
      int a = t >> 7, rem = t & 127;
      int q = rem >> 3, c8 = (rem & 7) << 3;
      const unsigned short* src = (a == 0) ? kg : vg;
      uint4 u = *(const uint4*)(src + ((size_t)(b * 2048 + t0 + q0 + q) * 16 + h) * 64 + c8);
      float* dst = (a == 0) ? &kb[q][c8] : &vb[q][c8];
      dst[0] = bf2f(u.x & 0xffff); dst[1] = bf2f(u.x >> 16);
      dst[2] = bf2f(u.y & 0xffff); dst[3] = bf2f(u.y >> 16);
      dst[4] = bf2f(u.z & 0xffff); dst[5] = bf2f(u.z >> 16);
      dst[6] = bf2f(u.w & 0xffff); dst[7] = bf2f(u.w >> 16);
    }
    __syncthreads();
    #pragma unroll
    for (int q = 0; q < 16; ++q) {
      float vj = vb[q][lane];
      const float4* kp = (const float4*)&kb[q][wv * 16];
      #pragma unroll
      for (int a4 = 0; a4 < 4; ++a4) {
        float4 k4 = kp[a4];
        s_i[a4*4+0] = fmaf(w_i[a4*4+0], s_i[a4*4+0], k4.x * vj);
        s_i[a4*4+1] = fmaf(w_i[a4*4+1], s_i[a4*4+1], k4.y * vj);
        s_i[a4*4+2] = fmaf(w_i[a4*4+2], s_i[a4*4+2], k4.z * vj);
        s_i[a4*4+3] = fmaf(w_i[a4*4+3], s_i[a4*4+3], k4.w * vj);
      }
    }
  }
  size_t base = (((size_t)(b * 16 + h) * 16 + c) * 64) * 64;
  #pragma unroll
  for (int i = 0; i < 16; ++i)
    states[base + (size_t)(wv * 16 + i) * 64 + lane] = s_i[i];
}

// ---------- scan pass 2: cross-chunk recurrence, in place (S_loc -> S_init) ----------
__global__ __launch_bounds__(256) void scan_pass2(const float* __restrict__ td,
                                                  float* __restrict__ states) {
  const int bh = blockIdx.x;
  const int h = bh & 15;
  const int t = threadIdx.x;
  float run[16], wl[16];
  #pragma unroll
  for (int i = 0; i < 16; ++i) {
    int kk = (t + i * 256) >> 6;
    wl[i] = expf(-128.f * expf(td[h * 64 + kk]));   // w^L, L=128
    run[i] = 0.f;
  }
  size_t base0 = (size_t)bh * 16 * 4096;
  for (int c = 0; c < 16; ++c) {
    size_t base = base0 + (size_t)c * 4096;
    #pragma unroll
    for (int i = 0; i < 16; ++i) {
      float tmp = states[base + t + i * 256];       // S_loc[c]
      states[base + t + i * 256] = run[i];          // -> S_init[c]
      run[i] = fmaf(wl[i], run[i], tmp);
    }
  }
}

// ---------- scan pass 3: outputs, init from S_init ----------
// lane: kq = lane&3 (k-slice of 16), jj = wv*16 + lane>>2 (v-col). shfl-reduce over 4 lanes.
__global__ __launch_bounds__(256) void scan_pass3(
    const unsigned short* __restrict__ rg,
    const unsigned short* __restrict__ kg,
    const unsigned short* __restrict__ vg,
    const float* __restrict__ td,
    const float* __restrict__ fa,
    const float* __restrict__ states,
    float* __restrict__ outb) {
  const int c = blockIdx.x, h = blockIdx.y, b = blockIdx.z;
  const int t = threadIdx.x, lane = t & 63, wv = t >> 6;
  const int kq = lane & 3;
  const int jj = wv * 16 + (lane >> 2);
  float w_i[16], u_i[16], s_i[16];
  size_t sbase = (((size_t)(b * 16 + h) * 16 + c) * 64) * 64;
  #pragma unroll
  for (int i = 0; i < 16; ++i) {
    int kk = kq * 16 + i;
    w_i[i] = expf(-expf(td[h * 64 + kk]));
    u_i[i] = fa[h * 64 + kk];
    s_i[i] = states[sbase + (size_t)kk * 64 + jj];
  }
  __shared__ __align__(16) float rb[16][64];
  __shared__ __align__(16) float kb[16][64];
  __shared__ __align__(16) float vb[16][64];
  const int t0 = c * 128;
  for (int q0 = 0; q0 < 128; q0 += 16) {
    __syncthreads();
    for (int ch = t; ch < 384; ch += 256) {
      int a = ch >> 7, rem = ch & 127;
      int q = rem >> 3, c8 = (rem & 7) << 3;
      const unsigned short* src = (a == 0) ? rg : ((a == 1) ? kg : vg);
      uint4 u = *(const uint4*)(src + ((size_t)(b * 2048 + t0 + q0 + q) * 16 + h) * 64 + c8);
      float* dst = (a == 0) ? &rb[q][c8] : ((a == 1) ? &kb[q][c8] : &vb[q][c8]);
      dst[0] = bf2f(u.x & 0xffff); dst[1] = bf2f(u.x >> 16);
      dst[2] = bf2f(u.y & 0xffff); dst[3] = bf2f(u.y >> 16);
      dst[4] = bf2f(u.z & 0xffff); dst[5] = bf2f(u.z >> 16);
      dst[6] = bf2f(u.w & 0xffff); dst[7] = bf2f(u.w >> 16);
    }
    __syncthreads();
    #pragma unroll
    for (int q = 0; q < 16; ++q) {
      float vj = vb[q][jj];
      const float4* rp = (const float4*)&rb[q][kq * 16];
      const float4* kp = (const float4*)&kb[q][kq * 16];
      float acc = 0.f;
      #pragma unroll
      for (int a4 = 0; a4 < 4; ++a4) {
        float4 r4 = rp[a4], k4 = kp[a4];
        { float kv = k4.x * vj; acc = fmaf(r4.x, fmaf(u_i[a4*4+0], kv, s_i[a4*4+0]), acc); s_i[a4*4+0] = fmaf(w_i[a4*4+0], s_i[a4*4+0], kv); }
        { float kv = k4.y * vj; acc = fmaf(r4.y, fmaf(u_i[a4*4+1], kv, s_i[a4*4+1]), acc); s_i[a4*4+1] = fmaf(w_i[a4*4+1], s_i[a4*4+1], kv); }
        { float kv = k4.z * vj; acc = fmaf(r4.z, fmaf(u_i[a4*4+2], kv, s_i[a4*4+2]), acc); s_i[a4*4+2] = fmaf(w_i[a4*4+2], s_i[a4*4+2], kv); }
        { float kv = k4.w * vj; acc = fmaf(r4.w, fmaf(u_i[a4*4+3], kv, s_i[a4*4+3]), acc); s_i[a4*4+3] = fmaf(w_i[a4*4+3], s_i[a4*4+3], kv); }
      }
      acc += __shfl_xor(acc, 1);
      acc += __shfl_xor(acc, 2);
      if (kq == 0)
        outb[((size_t)(b * 2048 + t0 + q0 + q) * 16 + h) * 64 + jj] = acc;
    }
  }
}

// ---------- groupnorm(S=64) + gate -> bf16 A5 ----------
__global__ __launch_bounds__(256) void gnorm_kernel(
    const float* __restrict__ outb,
    const unsigned short* __restrict__ gb,
    const float* __restrict__ lnw,
    const float* __restrict__ lnb,
    unsigned short* __restrict__ a5) {
  const int t = threadIdx.x, lane = t & 63, wv = t >> 6;
  const int grp = blockIdx.x * 4 + wv;      // [0, B*T*H)
  const int bt = grp >> 4, h = grp & 15;
  const size_t off = (size_t)bt * 1024 + h * 64 + lane;
  float y = outb[off] * 0.125f;             // / HEAD_SIZE_DIVISOR
  float s1 = y, s2 = y * y;
  #pragma unroll
  for (int d = 1; d < 64; d <<= 1) {
    s1 += __shfl_xor(s1, d);
    s2 += __shfl_xor(s2, d);
  }
  float mean = s1 * 0.015625f;
  float var  = s2 * 0.015625f - mean * mean;
  float rstd = rsqrtf(var + 1e-5f);
  float yn = (y - mean) * rstd * lnw[h * 64 + lane] + lnb[h * 64 + lane];
  a5[off] = f2bf(yn * bf2f(gb[off]));
}

extern "C" void kernel_launch(void* const* d_in, const int* in_sizes, int n_in,
                              void* d_out, int out_size, void* d_ws, size_t ws_size,
                              hipStream_t stream) {
  const float* xq  = (const float*)d_in[0];
  const float* tmk = (const float*)d_in[3];
  const float* tmv = (const float*)d_in[4];
  const float* tmr = (const float*)d_in[5];
  const float* tmg = (const float*)d_in[6];
  const float* td  = (const float*)d_in[7];
  const float* fa  = (const float*)d_in[8];
  const float* lnw = (const float*)d_in[14];
  const float* lnb = (const float*)d_in[15];

  // Workspace layout (total 178,257,920 B ≈ 170 MB):
  //   [0, 10.5MB)            WBF  : bf16 Wr,Wk,Wv,Wg,Wo (5 x 2MB)
  //   [10.5MB, 44MB)         SCR  : 32MB time-shared: AMIX (per-z mixed A, bf16)
  //                                 -> ST (chunk states, f32) -> A5 (gated gnorm out, bf16)
  //   [44MB, 172MB)          RKVG : r,k,v,g bf16 (4 x 32MB)
  // d_out (64MB f32) doubles as the scan-output buffer (overwritten by final GEMM).
  char* ws = (char*)d_ws;
  unsigned short* WBF  = (unsigned short*)(ws);
  char*           SCR  = ws + 10485760ull;
  unsigned short* RKVG = (unsigned short*)(ws + 44040192ull);
  unsigned short* AMIX = (unsigned short*)SCR;
  float*          ST   = (float*)SCR;
  unsigned short* A5   = (unsigned short*)SCR;
  float*          OUTB = (float*)d_out;

  for (int i = 0; i < 5; ++i)
    castw_kernel<<<1024, 256, 0, stream>>>((const float*)d_in[9 + i], WBF + (size_t)i * 1048576);

  const float* mixes[4] = {tmr, tmk, tmv, tmg};
  for (int z = 0; z < 4; ++z) {
    mix1_kernel<<<16384, 256, 0, stream>>>(xq, mixes[z], AMIX);
    gemm_kernel<<<dim3(8, 128), 256, 0, stream>>>(AMIX, WBF + (size_t)z * 1048576,
                                                  RKVG + (size_t)z * 16777216, (float*)nullptr,
                                                  (z == 3) ? 1 : 0, 0);
  }

  scan_pass1<<<dim3(16, 16, 8), 256, 0, stream>>>(RKVG + 16777216ull, RKVG + 33554432ull, td, ST);
  scan_pass2<<<128, 256, 0, stream>>>(td, ST);
  scan_pass3<<<dim3(16, 16, 8), 256, 0, stream>>>(RKVG, RKVG + 16777216ull, RKVG + 33554432ull,
                                                  td, fa, ST, OUTB);

  gnorm_kernel<<<65536, 256, 0, stream>>>(OUTB, RKVG + 50331648ull, lnw, lnb, A5);

  gemm_kernel<<<dim3(8, 128), 256, 0, stream>>>(A5, WBF + 4194304ull,
                                                (unsigned short*)nullptr, (float*)d_out, 0, 1);
}

// Round 3
// 748.108 us; speedup vs baseline: 1.1137x; 1.1137x over previous
//
#include <hip/hip_runtime.h>
#include <stdint.h>

using bf16x8 = __attribute__((ext_vector_type(8))) __bf16;
using f32x4  = __attribute__((ext_vector_type(4))) float;

__device__ __forceinline__ unsigned short f2bf(float f) {
  unsigned u = __float_as_uint(f);
  u = u + 0x7FFFu + ((u >> 16) & 1u);
  return (unsigned short)(u >> 16);
}
__device__ __forceinline__ float bf2f(unsigned short h) {
  return __uint_as_float(((unsigned)h) << 16);
}
__device__ __forceinline__ void gload16(const void* g, void* l) {
  __builtin_amdgcn_global_load_lds((const __attribute__((address_space(1))) void*)g,
                                   (__attribute__((address_space(3))) void*)l, 16, 0, 0);
}

// ---------- cast 5 f32 weight matrices -> bf16, one launch ----------
__global__ __launch_bounds__(256) void castw5_kernel(
    const float* __restrict__ w0, const float* __restrict__ w1,
    const float* __restrict__ w2, const float* __restrict__ w3,
    const float* __restrict__ w4, unsigned short* __restrict__ o) {
  const float* wsrc[5] = {w0, w1, w2, w3, w4};
  const float* w = wsrc[blockIdx.y];
  int i4 = blockIdx.x * 256 + threadIdx.x;
  float4 f = *(const float4*)(w + (size_t)i4 * 4);
  ushort4 u;
  u.x = f2bf(f.x); u.y = f2bf(f.y); u.z = f2bf(f.z); u.w = f2bf(f.w);
  *(ushort4*)(o + (size_t)blockIdx.y * 1048576 + (size_t)i4 * 4) = u;
}

// ---------- token-shift mix (single variant): amix[row][c] = x*m + xs*(1-m)  (bf16) ----------
__global__ __launch_bounds__(256) void mix1_kernel(const float* __restrict__ x,
                                                   const float* __restrict__ m,
                                                   unsigned short* __restrict__ amix) {
  int idx = blockIdx.x * 256 + threadIdx.x;   // [0, 4M)
  int row = idx >> 8;
  int c0  = (idx & 255) << 2;
  size_t xoff = (size_t)row * 1024 + c0;
  float4 xv = *(const float4*)(x + xoff);
  float4 xs = make_float4(0.f, 0.f, 0.f, 0.f);
  if ((row & 2047) != 0) xs = *(const float4*)(x + xoff - 1024);
  float4 mm = *(const float4*)(m + c0);
  ushort4 u;
  u.x = f2bf(xv.x * mm.x + xs.x * (1.f - mm.x));
  u.y = f2bf(xv.y * mm.y + xs.y * (1.f - mm.y));
  u.z = f2bf(xv.z * mm.z + xs.z * (1.f - mm.z));
  u.w = f2bf(xv.w * mm.w + xs.w * (1.f - mm.w));
  *(ushort4*)(amix + xoff) = u;
}

// ---------- bf16 NT GEMM: C[M=16384,N=1024] = A[M,K=1024] @ W[N,K]^T ----------
// 128x128 tile, BK=32, 4 waves, m97 structure (global_load_lds width 16).
__global__ __launch_bounds__(256) void gemm_kernel(
    const unsigned short* __restrict__ A,
    const unsigned short* __restrict__ W,
    unsigned short* __restrict__ Cbf,
    float* __restrict__ Cf,
    int do_silu, int f32out) {
  const int brow = blockIdx.y * 128;
  const int bcol = blockIdx.x * 128;
  const int t = threadIdx.x;
  const int lane = t & 63, wv = t >> 6;
  const int wr = wv >> 1, wc = wv & 1;
  const int lm = lane & 15, lk = lane >> 4;

  __shared__ __align__(16) unsigned short Al[128 * 32];
  __shared__ __align__(16) unsigned short Bl[128 * 32];

  f32x4 acc[4][4];
  const f32x4 z4 = {0.f, 0.f, 0.f, 0.f};
  #pragma unroll
  for (int mi = 0; mi < 4; ++mi)
    #pragma unroll
    for (int ni = 0; ni < 4; ++ni) acc[mi][ni] = z4;

  for (int kt = 0; kt < 32; ++kt) {
    __syncthreads();   // all waves done reading previous tile
    #pragma unroll
    for (int is = 0; is < 2; ++is) {
      int chunk = is * 256 + t;          // 16B chunk id within 8KB half
      int r  = chunk >> 2;               // row (4 chunks per 64B row)
      int c8 = (chunk & 3) << 3;         // bf16 col start
      int lb = (is * 256 + wv * 64) * 8; // wave-uniform LDS base (ushort units)
      gload16(A + (size_t)(brow + r) * 1024 + kt * 32 + c8, &Al[lb]);
      gload16(W + (size_t)(bcol + r) * 1024 + kt * 32 + c8, &Bl[lb]);
    }
    __syncthreads();   // barrier drains vmcnt(0) -> tile resident
    bf16x8 af[4], bfv[4];
    #pragma unroll
    for (int mi = 0; mi < 4; ++mi)
      af[mi] = *(const bf16x8*)&Al[(wr * 64 + mi * 16 + lm) * 32 + lk * 8];
    #pragma unroll
    for (int ni = 0; ni < 4; ++ni)
      bfv[ni] = *(const bf16x8*)&Bl[(wc * 64 + ni * 16 + lm) * 32 + lk * 8];
    #pragma unroll
    for (int mi = 0; mi < 4; ++mi)
      #pragma unroll
      for (int ni = 0; ni < 4; ++ni)
        acc[mi][ni] = __builtin_amdgcn_mfma_f32_16x16x32_bf16(af[mi], bfv[ni], acc[mi][ni], 0, 0, 0);
  }

  const int r0 = brow + wr * 64;
  const int c0 = bcol + wc * 64;
  #pragma unroll
  for (int mi = 0; mi < 4; ++mi) {
    #pragma unroll
    for (int ni = 0; ni < 4; ++ni) {
      #pragma unroll
      for (int rg = 0; rg < 4; ++rg) {
        int row = r0 + mi * 16 + lk * 4 + rg;   // C/D: col=lane&15, row=(lane>>4)*4+reg (m89)
        int col = c0 + ni * 16 + lm;
        float v = acc[mi][ni][rg];
        if (f32out) {
          Cf[(size_t)row * 1024 + col] = v;
        } else {
          if (do_silu) v = v / (1.f + expf(-v));   // silu for the gate
          Cbf[(size_t)row * 1024 + col] = f2bf(v);
        }
      }
    }
  }
}

// ---------- scan pass 1 (MFMA): S_loc[c] = sum_s w^{127-s} o (k_s v_s^T) ----------
// grid (NC=16, H=16, B=8), 4 waves. LDS holds kw^T and v^T [64 dims][128 tokens] bf16,
// token-blocks XOR-swizzled by (dimrow>>3)&7 so the transpose writes are bank-conflict-free.
__global__ __launch_bounds__(256) void scan_pass1(
    const unsigned short* __restrict__ kg,
    const unsigned short* __restrict__ vg,
    const float* __restrict__ td,
    float* __restrict__ states) {
  const int c = blockIdx.x, h = blockIdx.y, b = blockIdx.z;
  const int t = threadIdx.x, lane = t & 63, wv = t >> 6;
  __shared__ __align__(16) unsigned short kwT[64 * 128];
  __shared__ __align__(16) unsigned short vT[64 * 128];

  // ---- stage + scale + transpose ----
  const int a  = t & 7;          // dim-group: d0 = a*8
  const int d0 = a * 8;
  const int sb = t >> 3;         // token base (0..31)
  float eta[8];
  #pragma unroll
  for (int j = 0; j < 8; ++j) eta[j] = expf(td[h * 64 + d0 + j]);   // exp(time_decay)
  const int t0 = c * 128;
  #pragma unroll
  for (int i = 0; i < 4; ++i) {
    int s = sb + 32 * i;
    size_t goff = ((size_t)(b * 2048 + t0 + s) * 16 + h) * 64 + d0;
    uint4 ku = *(const uint4*)(kg + goff);
    uint4 vu = *(const uint4*)(vg + goff);
    unsigned short kv[8] = {(unsigned short)(ku.x & 0xffff), (unsigned short)(ku.x >> 16),
                            (unsigned short)(ku.y & 0xffff), (unsigned short)(ku.y >> 16),
                            (unsigned short)(ku.z & 0xffff), (unsigned short)(ku.z >> 16),
                            (unsigned short)(ku.w & 0xffff), (unsigned short)(ku.w >> 16)};
    unsigned short vv[8] = {(unsigned short)(vu.x & 0xffff), (unsigned short)(vu.x >> 16),
                            (unsigned short)(vu.y & 0xffff), (unsigned short)(vu.y >> 16),
                            (unsigned short)(vu.z & 0xffff), (unsigned short)(vu.z >> 16),
                            (unsigned short)(vu.w & 0xffff), (unsigned short)(vu.w >> 16)};
    float p = -(float)(127 - s);
    int ss = s ^ (a << 3);       // swizzled token column (row d has (d>>3)&7 == a)
    #pragma unroll
    for (int j = 0; j < 8; ++j) {
      float wpow = expf(p * eta[j]);                  // w^{127-s}; underflow->0 is exact enough
      kwT[(d0 + j) * 128 + ss] = f2bf(bf2f(kv[j]) * wpow);
      vT [(d0 + j) * 128 + ss] = vv[j];
    }
  }
  __syncthreads();

  // ---- MFMA: wave wv owns S rows [wv*16, wv*16+16) ----
  const int lm = lane & 15, lk = lane >> 4;
  const int aR = (wv * 2 + (lm >> 3)) & 7;            // swizzle key for kwT row
  f32x4 acc[4];
  const f32x4 z4 = {0.f, 0.f, 0.f, 0.f};
  #pragma unroll
  for (int ni = 0; ni < 4; ++ni) acc[ni] = z4;
  #pragma unroll
  for (int ks = 0; ks < 4; ++ks) {
    bf16x8 af = *(const bf16x8*)&kwT[(wv * 16 + lm) * 128 + (((ks * 4 + lk) ^ aR) << 3)];
    #pragma unroll
    for (int ni = 0; ni < 4; ++ni) {
      int aV = (ni * 2 + (lm >> 3)) & 7;
      bf16x8 bv = *(const bf16x8*)&vT[(ni * 16 + lm) * 128 + (((ks * 4 + lk) ^ aV) << 3)];
      acc[ni] = __builtin_amdgcn_mfma_f32_16x16x32_bf16(af, bv, acc[ni], 0, 0, 0);
    }
  }
  size_t base = (((size_t)(b * 16 + h) * 16 + c) * 64) * 64;
  #pragma unroll
  for (int ni = 0; ni < 4; ++ni)
    #pragma unroll
    for (int rg = 0; rg < 4; ++rg) {
      int row = wv * 16 + lk * 4 + rg;                // m89 C/D layout
      int col = ni * 16 + lm;
      states[base + (size_t)row * 64 + col] = acc[ni][rg];
    }
}

// ---------- scan pass 2: cross-chunk recurrence, in place (S_loc -> S_init) ----------
__global__ __launch_bounds__(256) void scan_pass2(const float* __restrict__ td,
                                                  float* __restrict__ states) {
  const int bh = blockIdx.x;
  const int h = bh & 15;
  const int t = threadIdx.x;
  float run[16], wl[16];
  #pragma unroll
  for (int i = 0; i < 16; ++i) {
    int kk = (t + i * 256) >> 6;
    wl[i] = expf(-128.f * expf(td[h * 64 + kk]));   // w^L, L=128
    run[i] = 0.f;
  }
  size_t base0 = (size_t)bh * 16 * 4096;
  for (int c = 0; c < 16; ++c) {
    size_t base = base0 + (size_t)c * 4096;
    #pragma unroll
    for (int i = 0; i < 16; ++i) {
      float tmp = states[base + t + i * 256];       // S_loc[c]
      states[base + t + i * 256] = run[i];          // -> S_init[c]
      run[i] = fmaf(wl[i], run[i], tmp);
    }
  }
}

// ---------- scan pass 3 + fused groupnorm/gate ----------
// lane: kq = lane&3 (k-slice of 16), jj = wv*16 + lane>>2 (v-col). shfl-reduce over 4 lanes.
// Epilogue per 16-row group: LDS out rows -> 16-lane reduce -> ln+gate, written IN PLACE over g.
__global__ __launch_bounds__(256) void scan_pass3(
    const unsigned short* __restrict__ rg,
    const unsigned short* __restrict__ kg,
    const unsigned short* __restrict__ vg,
    const float* __restrict__ td,
    const float* __restrict__ fa,
    const float* __restrict__ states,
    const float* __restrict__ lnw,
    const float* __restrict__ lnb,
    unsigned short* gbuf /* g in, gated-gnorm out (in place) */) {
  const int c = blockIdx.x, h = blockIdx.y, b = blockIdx.z;
  const int t = threadIdx.x, lane = t & 63, wv = t >> 6;
  const int kq = lane & 3;
  const int jj = wv * 16 + (lane >> 2);
  float w_i[16], u_i[16], s_i[16];
  size_t sbase = (((size_t)(b * 16 + h) * 16 + c) * 64) * 64;
  #pragma unroll
  for (int i = 0; i < 16; ++i) {
    int kk = kq * 16 + i;
    w_i[i] = expf(-expf(td[h * 64 + kk]));
    u_i[i] = fa[h * 64 + kk];
    s_i[i] = states[sbase + (size_t)kk * 64 + jj];
  }
  __shared__ __align__(16) float rb[16][64];
  __shared__ __align__(16) float kb[16][64];
  __shared__ __align__(16) float vb[16][64];
  __shared__ __align__(16) float ob[16][64];
  const int t0 = c * 128;
  for (int q0 = 0; q0 < 128; q0 += 16) {
    __syncthreads();           // protects rb/kb/vb AND ob reuse from previous iter
    for (int ch = t; ch < 384; ch += 256) {
      int a = ch >> 7, rem = ch & 127;
      int q = rem >> 3, c8 = (rem & 7) << 3;
      const unsigned short* src = (a == 0) ? rg : ((a == 1) ? kg : vg);
      uint4 u = *(const uint4*)(src + ((size_t)(b * 2048 + t0 + q0 + q) * 16 + h) * 64 + c8);
      float* dst = (a == 0) ? &rb[q][c8] : ((a == 1) ? &kb[q][c8] : &vb[q][c8]);
      dst[0] = bf2f(u.x & 0xffff); dst[1] = bf2f(u.x >> 16);
      dst[2] = bf2f(u.y & 0xffff); dst[3] = bf2f(u.y >> 16);
      dst[4] = bf2f(u.z & 0xffff); dst[5] = bf2f(u.z >> 16);
      dst[6] = bf2f(u.w & 0xffff); dst[7] = bf2f(u.w >> 16);
    }
    __syncthreads();
    #pragma unroll
    for (int q = 0; q < 16; ++q) {
      float vj = vb[q][jj];
      const float4* rp = (const float4*)&rb[q][kq * 16];
      const float4* kp = (const float4*)&kb[q][kq * 16];
      float acc = 0.f;
      #pragma unroll
      for (int a4 = 0; a4 < 4; ++a4) {
        float4 r4 = rp[a4], k4 = kp[a4];
        { float kv = k4.x * vj; acc = fmaf(r4.x, fmaf(u_i[a4*4+0], kv, s_i[a4*4+0]), acc); s_i[a4*4+0] = fmaf(w_i[a4*4+0], s_i[a4*4+0], kv); }
        { float kv = k4.y * vj; acc = fmaf(r4.y, fmaf(u_i[a4*4+1], kv, s_i[a4*4+1]), acc); s_i[a4*4+1] = fmaf(w_i[a4*4+1], s_i[a4*4+1], kv); }
        { float kv = k4.z * vj; acc = fmaf(r4.z, fmaf(u_i[a4*4+2], kv, s_i[a4*4+2]), acc); s_i[a4*4+2] = fmaf(w_i[a4*4+2], s_i[a4*4+2], kv); }
        { float kv = k4.w * vj; acc = fmaf(r4.w, fmaf(u_i[a4*4+3], kv, s_i[a4*4+3]), acc); s_i[a4*4+3] = fmaf(w_i[a4*4+3], s_i[a4*4+3], kv); }
      }
      acc += __shfl_xor(acc, 1);
      acc += __shfl_xor(acc, 2);
      if (kq == 0) ob[q][jj] = acc;
    }
    __syncthreads();
    // ---- fused groupnorm + gate over the 16 rows just produced ----
    {
      int r  = wv * 4 + (lane >> 4);           // row within q0 group
      int c4 = (lane & 15) * 4;                // 4 v-dims per lane
      float4 y4 = *(const float4*)&ob[r][c4];
      y4.x *= 0.125f; y4.y *= 0.125f; y4.z *= 0.125f; y4.w *= 0.125f;
      float s1 = y4.x + y4.y + y4.z + y4.w;
      float s2 = y4.x * y4.x + y4.y * y4.y + y4.z * y4.z + y4.w * y4.w;
      #pragma unroll
      for (int d = 1; d < 16; d <<= 1) {
        s1 += __shfl_xor(s1, d);
        s2 += __shfl_xor(s2, d);
      }
      float mean = s1 * 0.015625f;
      float var  = s2 * 0.015625f - mean * mean;
      float rstd = rsqrtf(var + 1e-5f);
      float4 lw = *(const float4*)(lnw + h * 64 + c4);
      float4 lb = *(const float4*)(lnb + h * 64 + c4);
      size_t go = ((size_t)(b * 2048 + t0 + q0 + r) * 16 + h) * 64 + c4;
      uint2 gu = *(const uint2*)(gbuf + go);
      float g0 = bf2f(gu.x & 0xffff), g1 = bf2f(gu.x >> 16);
      float g2 = bf2f(gu.y & 0xffff), g3 = bf2f(gu.y >> 16);
      ushort4 o;
      o.x = f2bf(((y4.x - mean) * rstd * lw.x + lb.x) * g0);
      o.y = f2bf(((y4.y - mean) * rstd * lw.y + lb.y) * g1);
      o.z = f2bf(((y4.z - mean) * rstd * lw.z + lb.z) * g2);
      o.w = f2bf(((y4.w - mean) * rstd * lw.w + lb.w) * g3);
      *(ushort4*)(gbuf + go) = o;              // in place: element-exclusive per lane
    }
  }
}

extern "C" void kernel_launch(void* const* d_in, const int* in_sizes, int n_in,
                              void* d_out, int out_size, void* d_ws, size_t ws_size,
                              hipStream_t stream) {
  const float* xq  = (const float*)d_in[0];
  const float* tmk = (const float*)d_in[3];
  const float* tmv = (const float*)d_in[4];
  const float* tmr = (const float*)d_in[5];
  const float* tmg = (const float*)d_in[6];
  const float* td  = (const float*)d_in[7];
  const float* fa  = (const float*)d_in[8];
  const float* lnw = (const float*)d_in[14];
  const float* lnb = (const float*)d_in[15];

  // Workspace layout (total ~170 MB):
  //   [0, 10.5MB)     WBF  : bf16 Wr,Wk,Wv,Wg,Wo (5 x 2MB)
  //   [10.5MB, 44MB)  SCR  : 32MB time-shared: AMIX (mixed A, bf16) -> ST (chunk states, f32)
  //   [44MB, 172MB)   RKVG : r,k,v,g bf16 (4 x 32MB); g gets gated-gnorm output IN PLACE.
  char* ws = (char*)d_ws;
  unsigned short* WBF  = (unsigned short*)(ws);
  char*           SCR  = ws + 10485760ull;
  unsigned short* RKVG = (unsigned short*)(ws + 44040192ull);
  unsigned short* AMIX = (unsigned short*)SCR;
  float*          ST   = (float*)SCR;

  castw5_kernel<<<dim3(1024, 5), 256, 0, stream>>>(
      (const float*)d_in[9], (const float*)d_in[10], (const float*)d_in[11],
      (const float*)d_in[12], (const float*)d_in[13], WBF);

  const float* mixes[4] = {tmr, tmk, tmv, tmg};
  for (int z = 0; z < 4; ++z) {
    mix1_kernel<<<16384, 256, 0, stream>>>(xq, mixes[z], AMIX);
    gemm_kernel<<<dim3(8, 128), 256, 0, stream>>>(AMIX, WBF + (size_t)z * 1048576,
                                                  RKVG + (size_t)z * 16777216, (float*)nullptr,
                                                  (z == 3) ? 1 : 0, 0);
  }

  scan_pass1<<<dim3(16, 16, 8), 256, 0, stream>>>(RKVG + 16777216ull, RKVG + 33554432ull, td, ST);
  scan_pass2<<<128, 256, 0, stream>>>(td, ST);
  scan_pass3<<<dim3(16, 16, 8), 256, 0, stream>>>(RKVG, RKVG + 16777216ull, RKVG + 33554432ull,
                                                  td, fa, ST, lnw, lnb, RKVG + 50331648ull);

  gemm_kernel<<<dim3(8, 128), 256, 0, stream>>>(RKVG + 50331648ull, WBF + 4194304ull,
                                                (unsigned short*)nullptr, (float*)d_out, 0, 1);
}

// Round 6
// 727.070 us; speedup vs baseline: 1.1459x; 1.0289x over previous
//
#include <hip/hip_runtime.h>
#include <stdint.h>

using bf16x8 = __attribute__((ext_vector_type(8))) __bf16;
using f32x4  = __attribute__((ext_vector_type(4))) float;

__device__ __forceinline__ unsigned short f2bf(float f) {
  unsigned u = __float_as_uint(f);
  u = u + 0x7FFFu + ((u >> 16) & 1u);
  return (unsigned short)(u >> 16);
}
__device__ __forceinline__ float bf2f(unsigned short h) {
  return __uint_as_float(((unsigned)h) << 16);
}
__device__ __forceinline__ void gload16(const void* g, void* l) {
  __builtin_amdgcn_global_load_lds((const __attribute__((address_space(1))) void*)g,
                                   (__attribute__((address_space(3))) void*)l, 16, 0, 0);
}

// ---------- cast 5 f32 weight matrices -> bf16, one launch ----------
__global__ __launch_bounds__(256) void castw5_kernel(
    const float* __restrict__ w0, const float* __restrict__ w1,
    const float* __restrict__ w2, const float* __restrict__ w3,
    const float* __restrict__ w4, unsigned short* __restrict__ o) {
  const float* wsrc[5] = {w0, w1, w2, w3, w4};
  const float* w = wsrc[blockIdx.y];
  int i4 = blockIdx.x * 256 + threadIdx.x;
  float4 f = *(const float4*)(w + (size_t)i4 * 4);
  ushort4 u;
  u.x = f2bf(f.x); u.y = f2bf(f.y); u.z = f2bf(f.z); u.w = f2bf(f.w);
  *(ushort4*)(o + (size_t)blockIdx.y * 1048576 + (size_t)i4 * 4) = u;
}

// ---------- token-shift mix (single variant): amix[row][c] = x*m + xs*(1-m)  (bf16) ----------
__global__ __launch_bounds__(256) void mix1_kernel(const float* __restrict__ x,
                                                   const float* __restrict__ m,
                                                   unsigned short* __restrict__ amix) {
  int idx = blockIdx.x * 256 + threadIdx.x;   // [0, 4M)
  int row = idx >> 8;
  int c0  = (idx & 255) << 2;
  size_t xoff = (size_t)row * 1024 + c0;
  float4 xv = *(const float4*)(x + xoff);
  float4 xs = make_float4(0.f, 0.f, 0.f, 0.f);
  if ((row & 2047) != 0) xs = *(const float4*)(x + xoff - 1024);
  float4 mm = *(const float4*)(m + c0);
  ushort4 u;
  u.x = f2bf(xv.x * mm.x + xs.x * (1.f - mm.x));
  u.y = f2bf(xv.y * mm.y + xs.y * (1.f - mm.y));
  u.z = f2bf(xv.z * mm.z + xs.z * (1.f - mm.z));
  u.w = f2bf(xv.w * mm.w + xs.w * (1.f - mm.w));
  *(ushort4*)(amix + xoff) = u;
}

// ---------- bf16 NT GEMM: C[M=16384,N=1024] = A[M,K=1024] @ W[N,K]^T ----------
// 128x128 tile, BK=32, 4 waves, m97 structure + XCD-aware block swizzle (bijective: 1024%8==0).
__global__ __launch_bounds__(256) void gemm_kernel(
    const unsigned short* __restrict__ A,
    const unsigned short* __restrict__ W,
    unsigned short* __restrict__ Cbf,
    float* __restrict__ Cf,
    int do_silu, int f32out) {
  int orig = blockIdx.y * gridDim.x + blockIdx.x;
  int cpx  = (gridDim.x * gridDim.y) >> 3;
  int wg   = (orig & 7) * cpx + (orig >> 3);
  const int brow = (wg / gridDim.x) * 128;
  const int bcol = (wg % gridDim.x) * 128;
  const int t = threadIdx.x;
  const int lane = t & 63, wv = t >> 6;
  const int wr = wv >> 1, wc = wv & 1;
  const int lm = lane & 15, lk = lane >> 4;

  __shared__ __align__(16) unsigned short Al[128 * 32];
  __shared__ __align__(16) unsigned short Bl[128 * 32];

  f32x4 acc[4][4];
  const f32x4 z4 = {0.f, 0.f, 0.f, 0.f};
  #pragma unroll
  for (int mi = 0; mi < 4; ++mi)
    #pragma unroll
    for (int ni = 0; ni < 4; ++ni) acc[mi][ni] = z4;

  for (int kt = 0; kt < 32; ++kt) {
    __syncthreads();   // all waves done reading previous tile
    #pragma unroll
    for (int is = 0; is < 2; ++is) {
      int chunk = is * 256 + t;          // 16B chunk id within 8KB half
      int r  = chunk >> 2;               // row (4 chunks per 64B row)
      int c8 = (chunk & 3) << 3;         // bf16 col start
      int lb = (is * 256 + wv * 64) * 8; // wave-uniform LDS base (ushort units)
      gload16(A + (size_t)(brow + r) * 1024 + kt * 32 + c8, &Al[lb]);
      gload16(W + (size_t)(bcol + r) * 1024 + kt * 32 + c8, &Bl[lb]);
    }
    __syncthreads();   // barrier drains vmcnt(0) -> tile resident
    bf16x8 af[4], bfv[4];
    #pragma unroll
    for (int mi = 0; mi < 4; ++mi)
      af[mi] = *(const bf16x8*)&Al[(wr * 64 + mi * 16 + lm) * 32 + lk * 8];
    #pragma unroll
    for (int ni = 0; ni < 4; ++ni)
      bfv[ni] = *(const bf16x8*)&Bl[(wc * 64 + ni * 16 + lm) * 32 + lk * 8];
    #pragma unroll
    for (int mi = 0; mi < 4; ++mi)
      #pragma unroll
      for (int ni = 0; ni < 4; ++ni)
        acc[mi][ni] = __builtin_amdgcn_mfma_f32_16x16x32_bf16(af[mi], bfv[ni], acc[mi][ni], 0, 0, 0);
  }

  const int r0 = brow + wr * 64;
  const int c0 = bcol + wc * 64;
  #pragma unroll
  for (int mi = 0; mi < 4; ++mi) {
    #pragma unroll
    for (int ni = 0; ni < 4; ++ni) {
      #pragma unroll
      for (int rg = 0; rg < 4; ++rg) {
        int row = r0 + mi * 16 + lk * 4 + rg;   // C/D: col=lane&15, row=(lane>>4)*4+reg (m89)
        int col = c0 + ni * 16 + lm;
        float v = acc[mi][ni][rg];
        if (f32out) {
          Cf[(size_t)row * 1024 + col] = v;
        } else {
          if (do_silu) v = v / (1.f + expf(-v));   // silu for the gate
          Cbf[(size_t)row * 1024 + col] = f2bf(v);
        }
      }
    }
  }
}

// ---------- scan pass 1 (MFMA): S_loc[c] = sum_s w^{127-s} o (k_s v_s^T) ----------
__global__ __launch_bounds__(256) void scan_pass1(
    const unsigned short* __restrict__ kg,
    const unsigned short* __restrict__ vg,
    const float* __restrict__ td,
    float* __restrict__ states) {
  const int c = blockIdx.x, h = blockIdx.y, b = blockIdx.z;
  const int t = threadIdx.x, lane = t & 63, wv = t >> 6;
  __shared__ __align__(16) unsigned short kwT[64 * 128];
  __shared__ __align__(16) unsigned short vT[64 * 128];

  const int a  = t & 7;
  const int d0 = a * 8;
  const int sb = t >> 3;
  float eta[8];
  #pragma unroll
  for (int j = 0; j < 8; ++j) eta[j] = expf(td[h * 64 + d0 + j]);
  const int t0 = c * 128;
  #pragma unroll
  for (int i = 0; i < 4; ++i) {
    int s = sb + 32 * i;
    size_t goff = ((size_t)(b * 2048 + t0 + s) * 16 + h) * 64 + d0;
    uint4 ku = *(const uint4*)(kg + goff);
    uint4 vu = *(const uint4*)(vg + goff);
    unsigned short kv[8] = {(unsigned short)(ku.x & 0xffff), (unsigned short)(ku.x >> 16),
                            (unsigned short)(ku.y & 0xffff), (unsigned short)(ku.y >> 16),
                            (unsigned short)(ku.z & 0xffff), (unsigned short)(ku.z >> 16),
                            (unsigned short)(ku.w & 0xffff), (unsigned short)(ku.w >> 16)};
    unsigned short vv[8] = {(unsigned short)(vu.x & 0xffff), (unsigned short)(vu.x >> 16),
                            (unsigned short)(vu.y & 0xffff), (unsigned short)(vu.y >> 16),
                            (unsigned short)(vu.z & 0xffff), (unsigned short)(vu.z >> 16),
                            (unsigned short)(vu.w & 0xffff), (unsigned short)(vu.w >> 16)};
    float p = -(float)(127 - s);
    int ss = s ^ (a << 3);
    #pragma unroll
    for (int j = 0; j < 8; ++j) {
      float wpow = expf(p * eta[j]);
      kwT[(d0 + j) * 128 + ss] = f2bf(bf2f(kv[j]) * wpow);
      vT [(d0 + j) * 128 + ss] = vv[j];
    }
  }
  __syncthreads();

  const int lm = lane & 15, lk = lane >> 4;
  const int aR = (wv * 2 + (lm >> 3)) & 7;
  f32x4 acc[4];
  const f32x4 z4 = {0.f, 0.f, 0.f, 0.f};
  #pragma unroll
  for (int ni = 0; ni < 4; ++ni) acc[ni] = z4;
  #pragma unroll
  for (int ks = 0; ks < 4; ++ks) {
    bf16x8 af = *(const bf16x8*)&kwT[(wv * 16 + lm) * 128 + (((ks * 4 + lk) ^ aR) << 3)];
    #pragma unroll
    for (int ni = 0; ni < 4; ++ni) {
      int aV = (ni * 2 + (lm >> 3)) & 7;
      bf16x8 bv = *(const bf16x8*)&vT[(ni * 16 + lm) * 128 + (((ks * 4 + lk) ^ aV) << 3)];
      acc[ni] = __builtin_amdgcn_mfma_f32_16x16x32_bf16(af, bv, acc[ni], 0, 0, 0);
    }
  }
  size_t base = (((size_t)(b * 16 + h) * 16 + c) * 64) * 64;
  #pragma unroll
  for (int ni = 0; ni < 4; ++ni)
    #pragma unroll
    for (int rg = 0; rg < 4; ++rg) {
      int row = wv * 16 + lk * 4 + rg;
      int col = ni * 16 + lm;
      states[base + (size_t)row * 64 + col] = acc[ni][rg];
    }
}

// ---------- scan pass 2: cross-chunk recurrence, in place (S_loc -> S_init) ----------
__global__ __launch_bounds__(256) void scan_pass2(const float* __restrict__ td,
                                                  float* __restrict__ states) {
  const int bh = blockIdx.x;
  const int h = bh & 15;
  const int t = threadIdx.x;
  float run[16], wl[16];
  #pragma unroll
  for (int i = 0; i < 16; ++i) {
    int kk = (t + i * 256) >> 6;
    wl[i] = expf(-128.f * expf(td[h * 64 + kk]));
    run[i] = 0.f;
  }
  size_t base0 = (size_t)bh * 16 * 4096;
  for (int c = 0; c < 16; ++c) {
    size_t base = base0 + (size_t)c * 4096;
    #pragma unroll
    for (int i = 0; i < 16; ++i) {
      float tmp = states[base + t + i * 256];
      states[base + t + i * 256] = run[i];
      run[i] = fmaf(wl[i], run[i], tmp);
    }
  }
}

// ---------- scan pass 3 (serial f32, R3-proven) + fused groupnorm/gate ----------
// lane: kq = lane&3 (k-slice of 16), jj = wv*16 + lane>>2 (v-col). shfl-reduce over 4 lanes.
__global__ __launch_bounds__(256) void scan_pass3(
    const unsigned short* __restrict__ rg,
    const unsigned short* __restrict__ kg,
    const unsigned short* __restrict__ vg,
    const float* __restrict__ td,
    const float* __restrict__ fa,
    const float* __restrict__ states,
    const float* __restrict__ lnw,
    const float* __restrict__ lnb,
    unsigned short* gbuf /* g in, gated-gnorm out (in place) */) {
  const int c = blockIdx.x, h = blockIdx.y, b = blockIdx.z;
  const int t = threadIdx.x, lane = t & 63, wv = t >> 6;
  const int kq = lane & 3;
  const int jj = wv * 16 + (lane >> 2);
  float w_i[16], u_i[16], s_i[16];
  size_t sbase = (((size_t)(b * 16 + h) * 16 + c) * 64) * 64;
  #pragma unroll
  for (int i = 0; i < 16; ++i) {
    int kk = kq * 16 + i;
    w_i[i] = expf(-expf(td[h * 64 + kk]));
    u_i[i] = fa[h * 64 + kk];
    s_i[i] = states[sbase + (size_t)kk * 64 + jj];
  }
  __shared__ __align__(16) float rb[16][64];
  __shared__ __align__(16) float kb[16][64];
  __shared__ __align__(16) float vb[16][64];
  __shared__ __align__(16) float ob[16][64];
  const int t0 = c * 128;
  for (int q0 = 0; q0 < 128; q0 += 16) {
    __syncthreads();           // protects rb/kb/vb AND ob reuse from previous iter
    for (int ch = t; ch < 384; ch += 256) {
      int a = ch >> 7, rem = ch & 127;
      int q = rem >> 3, c8 = (rem & 7) << 3;
      const unsigned short* src = (a == 0) ? rg : ((a == 1) ? kg : vg);
      uint4 u = *(const uint4*)(src + ((size_t)(b * 2048 + t0 + q0 + q) * 16 + h) * 64 + c8);
      float* dst = (a == 0) ? &rb[q][c8] : ((a == 1) ? &kb[q][c8] : &vb[q][c8]);
      dst[0] = bf2f(u.x & 0xffff); dst[1] = bf2f(u.x >> 16);
      dst[2] = bf2f(u.y & 0xffff); dst[3] = bf2f(u.y >> 16);
      dst[4] = bf2f(u.z & 0xffff); dst[5] = bf2f(u.z >> 16);
      dst[6] = bf2f(u.w & 0xffff); dst[7] = bf2f(u.w >> 16);
    }
    __syncthreads();
    #pragma unroll
    for (int q = 0; q < 16; ++q) {
      float vj = vb[q][jj];
      const float4* rp = (const float4*)&rb[q][kq * 16];
      const float4* kp = (const float4*)&kb[q][kq * 16];
      float acc = 0.f;
      #pragma unroll
      for (int a4 = 0; a4 < 4; ++a4) {
        float4 r4 = rp[a4], k4 = kp[a4];
        { float kv = k4.x * vj; acc = fmaf(r4.x, fmaf(u_i[a4*4+0], kv, s_i[a4*4+0]), acc); s_i[a4*4+0] = fmaf(w_i[a4*4+0], s_i[a4*4+0], kv); }
        { float kv = k4.y * vj; acc = fmaf(r4.y, fmaf(u_i[a4*4+1], kv, s_i[a4*4+1]), acc); s_i[a4*4+1] = fmaf(w_i[a4*4+1], s_i[a4*4+1], kv); }
        { float kv = k4.z * vj; acc = fmaf(r4.z, fmaf(u_i[a4*4+2], kv, s_i[a4*4+2]), acc); s_i[a4*4+2] = fmaf(w_i[a4*4+2], s_i[a4*4+2], kv); }
        { float kv = k4.w * vj; acc = fmaf(r4.w, fmaf(u_i[a4*4+3], kv, s_i[a4*4+3]), acc); s_i[a4*4+3] = fmaf(w_i[a4*4+3], s_i[a4*4+3], kv); }
      }
      acc += __shfl_xor(acc, 1);
      acc += __shfl_xor(acc, 2);
      if (kq == 0) ob[q][jj] = acc;
    }
    __syncthreads();
    // ---- fused groupnorm + gate over the 16 rows just produced ----
    {
      int r  = wv * 4 + (lane >> 4);           // row within q0 group
      int c4 = (lane & 15) * 4;                // 4 v-dims per lane
      float4 y4 = *(const float4*)&ob[r][c4];
      y4.x *= 0.125f; y4.y *= 0.125f; y4.z *= 0.125f; y4.w *= 0.125f;
      float s1 = y4.x + y4.y + y4.z + y4.w;
      float s2 = y4.x * y4.x + y4.y * y4.y + y4.z * y4.z + y4.w * y4.w;
      #pragma unroll
      for (int d = 1; d < 16; d <<= 1) {
        s1 += __shfl_xor(s1, d);
        s2 += __shfl_xor(s2, d);
      }
      float mean = s1 * 0.015625f;
      float var  = s2 * 0.015625f - mean * mean;
      float rstd = rsqrtf(var + 1e-5f);
      float4 lw = *(const float4*)(lnw + h * 64 + c4);
      float4 lb = *(const float4*)(lnb + h * 64 + c4);
      size_t go = ((size_t)(b * 2048 + t0 + q0 + r) * 16 + h) * 64 + c4;
      uint2 gu = *(const uint2*)(gbuf + go);
      float g0 = bf2f(gu.x & 0xffff), g1 = bf2f(gu.x >> 16);
      float g2 = bf2f(gu.y & 0xffff), g3 = bf2f(gu.y >> 16);
      ushort4 o;
      o.x = f2bf(((y4.x - mean) * rstd * lw.x + lb.x) * g0);
      o.y = f2bf(((y4.y - mean) * rstd * lw.y + lb.y) * g1);
      o.z = f2bf(((y4.z - mean) * rstd * lw.z + lb.z) * g2);
      o.w = f2bf(((y4.w - mean) * rstd * lw.w + lb.w) * g3);
      *(ushort4*)(gbuf + go) = o;              // in place: element-exclusive per lane
    }
  }
}

extern "C" void kernel_launch(void* const* d_in, const int* in_sizes, int n_in,
                              void* d_out, int out_size, void* d_ws, size_t ws_size,
                              hipStream_t stream) {
  const float* xq  = (const float*)d_in[0];
  const float* tmk = (const float*)d_in[3];
  const float* tmv = (const float*)d_in[4];
  const float* tmr = (const float*)d_in[5];
  const float* tmg = (const float*)d_in[6];
  const float* td  = (const float*)d_in[7];
  const float* fa  = (const float*)d_in[8];
  const float* lnw = (const float*)d_in[14];
  const float* lnb = (const float*)d_in[15];

  // Workspace layout (~170 MB): WBF 10.5MB | SCR 32MB (AMIX -> ST) | RKVG 128MB
  char* ws = (char*)d_ws;
  unsigned short* WBF  = (unsigned short*)(ws);
  char*           SCR  = ws + 10485760ull;
  unsigned short* RKVG = (unsigned short*)(ws + 44040192ull);
  unsigned short* AMIX = (unsigned short*)SCR;
  float*          ST   = (float*)SCR;

  castw5_kernel<<<dim3(1024, 5), 256, 0, stream>>>(
      (const float*)d_in[9], (const float*)d_in[10], (const float*)d_in[11],
      (const float*)d_in[12], (const float*)d_in[13], WBF);

  const float* mixes[4] = {tmr, tmk, tmv, tmg};
  for (int z = 0; z < 4; ++z) {
    mix1_kernel<<<16384, 256, 0, stream>>>(xq, mixes[z], AMIX);
    gemm_kernel<<<dim3(8, 128), 256, 0, stream>>>(AMIX, WBF + (size_t)z * 1048576,
                                                  RKVG + (size_t)z * 16777216, (float*)nullptr,
                                                  (z == 3) ? 1 : 0, 0);
  }

  scan_pass1<<<dim3(16, 16, 8), 256, 0, stream>>>(RKVG + 16777216ull, RKVG + 33554432ull, td, ST);
  scan_pass2<<<128, 256, 0, stream>>>(td, ST);
  scan_pass3<<<dim3(16, 16, 8), 256, 0, stream>>>(RKVG, RKVG + 16777216ull, RKVG + 33554432ull,
                                                  td, fa, ST, lnw, lnb, RKVG + 50331648ull);

  gemm_kernel<<<dim3(8, 128), 256, 0, stream>>>(RKVG + 50331648ull, WBF + 4194304ull,
                                                (unsigned short*)nullptr, (float*)d_out, 0, 1);
}